// Round 3
// baseline (384.491 us; speedup 1.0000x reference)
//
#include <hip/hip_runtime.h>
#include <hip/hip_bf16.h>
#include <stdint.h>

// ---------------- db4 filter constants ----------------
__device__ __constant__ float c_DL[8] = {
    -0.010597401784997278f, 0.032883011666982945f, 0.030841381835986965f,
    -0.18703481171888114f, -0.02798376941698385f, 0.6308807679295904f,
    0.7148465705525415f, 0.23037781330885523f};
__device__ __constant__ float c_DH[8] = {
    -0.23037781330885523f, 0.7148465705525415f, -0.6308807679295904f,
    -0.02798376941698385f, 0.18703481171888114f, 0.030841381835986965f,
    -0.032883011666982945f, -0.010597401784997278f};
// REC_LO = reverse(DEC_LO), REC_HI = reverse(DEC_HI)
__device__ __constant__ float c_RL[8] = {
    0.23037781330885523f, 0.7148465705525415f, 0.6308807679295904f,
    -0.02798376941698385f, -0.18703481171888114f, 0.030841381835986965f,
    0.032883011666982945f, -0.010597401784997278f};
__device__ __constant__ float c_RH[8] = {
    -0.010597401784997278f, -0.032883011666982945f, 0.030841381835986965f,
    0.18703481171888114f, -0.02798376941698385f, -0.6308807679295904f,
    0.7148465705525415f, -0.23037781330885523f};

__device__ __forceinline__ float ldf(const float* p, size_t i) { return p[i]; }
__device__ __forceinline__ float ldf(const __hip_bfloat16* p, size_t i) { return __bfloat162float(p[i]); }
__device__ __forceinline__ void stf(float* p, size_t i, float v) { p[i] = v; }
__device__ __forceinline__ void stf(__hip_bfloat16* p, size_t i, float v) { p[i] = __float2bfloat16(v); }

__device__ __forceinline__ int reflect_idx(int t, int n) {
  if (t < 0) t = -1 - t;
  if (t >= n) t = 2 * n - 1 - t;
  return t;
}

// ---------------- Level-1 DWT: x (B,N,C) fp32, transposed read -> a1,d1 (B*C,4099) bf16
#define NT1 134
__global__ __launch_bounds__(256) void k_dwt_first(const float* __restrict__ x,
                                                   __hip_bfloat16* __restrict__ outa,
                                                   __hip_bfloat16* __restrict__ outd) {
  const int b = blockIdx.y;
  const int k0 = blockIdx.x * 64;
  const int tid = threadIdx.x;
  __shared__ float xs[NT1 * 65];

  const float4* x4 = (const float4*)x;
  for (int idx = tid; idx < NT1 * 16; idx += 256) {
    int nl = idx >> 4, cq = idx & 15;
    int t = 2 * k0 - 6 + nl;
    int n = reflect_idx(t, 8192);
    float4 v = x4[((size_t)b * 8192 + n) * 16 + cq];
    float* d = &xs[nl * 65 + 4 * cq];
    d[0] = v.x; d[1] = v.y; d[2] = v.z; d[3] = v.w;
  }
  __syncthreads();

  const int kk = tid & 63;
  const int k = k0 + kk;
  if (k >= 4099) return;
  for (int c = (tid >> 6); c < 64; c += 4) {
    float lo = 0.f, hi = 0.f;
#pragma unroll
    for (int j = 0; j < 8; ++j) {
      float v = xs[(2 * kk + 7 - j) * 65 + c];
      lo += c_DL[j] * v;
      hi += c_DH[j] * v;
    }
    size_t s = (size_t)b * 64 + c;
    outa[s * 4099 + k] = __float2bfloat16(lo);
    outd[s * 4099 + k] = __float2bfloat16(hi);
  }
}

// ---------------- Generic DWT level on rows (2048, n) -> (2048, m)
template <typename TIn, typename TOut>
__global__ void k_dwt(const TIn* __restrict__ in, TOut* __restrict__ outa,
                      TOut* __restrict__ outd, int n, int m) {
  int k = blockIdx.x * blockDim.x + threadIdx.x;
  if (k >= m) return;
  const TIn* row = in + (size_t)blockIdx.y * n;
  float lo = 0.f, hi = 0.f;
#pragma unroll
  for (int j = 0; j < 8; ++j) {
    int t = 2 * k + 1 - j;
    t = (t < 0) ? (-1 - t) : t;
    t = (t >= n) ? (2 * n - 1 - t) : t;
    float v = ldf(row, t);
    lo += c_DL[j] * v;
    hi += c_DH[j] * v;
  }
  stf(outa, (size_t)blockIdx.y * m + k, lo);
  stf(outd, (size_t)blockIdx.y * m + k, hi);
}

// ---------------- Channel mixing on coarsest coeffs (w1,w2 fp32)
__global__ void k_mix(const float* __restrict__ a4, const float* __restrict__ d4,
                      const float* __restrict__ w1, const float* __restrict__ w2,
                      float* __restrict__ am, float* __restrict__ dm) {
  int idx = blockIdx.x * blockDim.x + threadIdx.x;
  if (idx >= 64 * 518) return;
  int b = blockIdx.y;
  int o = idx / 518;
  int p = idx - o * 518;
  float sa = 0.f, sd = 0.f;
  for (int i = 0; i < 64; ++i) {
    float av = a4[(size_t)(b * 64 + i) * 518 + p];
    float dv = d4[(size_t)(b * 64 + i) * 518 + p];
    sa += av * w1[(size_t)(i * 64 + o) * 518 + p];
    sd += dv * w2[(size_t)(i * 64 + o) * 518 + p];
  }
  am[(size_t)(b * 64 + o) * 518 + p] = sa;
  dm[(size_t)(b * 64 + o) * 518 + p] = sd;
}

// ---------------- Generic IDWT level (fully interior due to reference crop)
template <typename TCa, typename TCd, typename TOut>
__global__ void k_idwt(const TCa* __restrict__ ca, const TCd* __restrict__ cd,
                       TOut* __restrict__ out, int m, int out_len) {
  int s = blockIdx.x * blockDim.x + threadIdx.x;
  if (s >= out_len) return;
  const TCa* pa = ca + (size_t)blockIdx.y * m;
  const TCd* pd = cd + (size_t)blockIdx.y * m;
  int u = s >> 1, par = s & 1;
  float acc = 0.f;
#pragma unroll
  for (int r = 0; r < 4; ++r) {
    int i = u + 3 - r;
    float fl = par ? c_RL[2 * r + 1] : c_RL[2 * r];
    float fh = par ? c_RH[2 * r + 1] : c_RH[2 * r];
    acc += fl * ldf(pa, i) + fh * ldf(pd, i);
  }
  stf(out, (size_t)blockIdx.y * out_len + s, acc);
}

// ---------------- Epilogue: final IDWT (4099 -> 8192) + Dense shortcut + mish -> fp32
__global__ __launch_bounds__(256) void k_epilogue(const __hip_bfloat16* __restrict__ r1,
                                                  const __hip_bfloat16* __restrict__ dd1,
                                                  const float* __restrict__ x,
                                                  const float* __restrict__ dk,
                                                  const float* __restrict__ bias,
                                                  float* __restrict__ out) {
  const int b = blockIdx.y;
  const int tile = blockIdx.x;
  const int n0 = tile * 64;
  const int u0 = n0 >> 1;
  const int tid = threadIdx.x;

  __shared__ float Ks[64 * 64];    // Ks[c][o]
  __shared__ float xs_t[64 * 66];  // xs_t[c][nn], padded stride 66
  __shared__ float ra[35 * 64];    // ra[i][o]
  __shared__ float rd[35 * 64];

  const float4* dk4 = (const float4*)dk;
  for (int idx = tid; idx < 1024; idx += 256) {
    int c = idx >> 4, cq = idx & 15;
    float4 v = dk4[idx];
    float* d = &Ks[c * 64 + 4 * cq];
    d[0] = v.x; d[1] = v.y; d[2] = v.z; d[3] = v.w;
  }
  const float4* x4 = (const float4*)x;
  for (int idx = tid; idx < 1024; idx += 256) {
    int nn = idx >> 4, cq = idx & 15;
    float4 v = x4[((size_t)b * 8192 + n0 + nn) * 16 + cq];
    xs_t[(4 * cq + 0) * 66 + nn] = v.x;
    xs_t[(4 * cq + 1) * 66 + nn] = v.y;
    xs_t[(4 * cq + 2) * 66 + nn] = v.z;
    xs_t[(4 * cq + 3) * 66 + nn] = v.w;
  }
  {
    int o2 = tid >> 2, il0 = tid & 3;
    const __hip_bfloat16* pr = r1 + (size_t)(b * 64 + o2) * 4099 + u0;
    const __hip_bfloat16* pd = dd1 + (size_t)(b * 64 + o2) * 4099 + u0;
    for (int il = il0; il < 35; il += 4) {
      ra[il * 64 + o2] = __bfloat162float(pr[il]);
      rd[il * 64 + o2] = __bfloat162float(pd[il]);
    }
  }
  __syncthreads();

  const int o = tid & 63;
  const int nb = tid >> 6;  // this thread handles nn = 16*nb + q, q=0..15
  const float bo = bias[o];

  float acc[16];
#pragma unroll
  for (int q = 0; q < 16; ++q) acc[q] = 0.f;

  for (int c = 0; c < 64; ++c) {
    float kc = Ks[c * 64 + o];
    const float2* px = (const float2*)&xs_t[c * 66 + 16 * nb];
#pragma unroll
    for (int h = 0; h < 8; ++h) {
      float2 v = px[h];
      acc[2 * h]     += v.x * kc;
      acc[2 * h + 1] += v.y * kc;
    }
  }

#pragma unroll
  for (int q = 0; q < 16; ++q) {
    int nn = 16 * nb + q;
    int ul = nn >> 1;  // i = ul+3-r in [0,34]
    float w = 0.f;
#pragma unroll
    for (int r = 0; r < 4; ++r) {
      int i = ul + 3 - r;
      float fl = (q & 1) ? c_RL[2 * r + 1] : c_RL[2 * r];
      float fh = (q & 1) ? c_RH[2 * r + 1] : c_RH[2 * r];
      w += fl * ra[i * 64 + o] + fh * rd[i * 64 + o];
    }
    float v = acc[q] + w + bo;
    // mish(v) = v * tanh(softplus(v)); tanh(ln(1+t)) = (t^2+2t)/(t^2+2t+2), t=e^v
    float t = __expf(fminf(v, 15.f));
    float num = t * (t + 2.f);
    float mm = (v > 15.f) ? v : v * (num / (num + 2.f));
    out[((size_t)b * 8192 + n0 + nn) * 64 + o] = mm;
  }
}

// ---------------- host ----------------
extern "C" void kernel_launch(void* const* d_in, const int* in_sizes, int n_in,
                              void* d_out, int out_size, void* d_ws, size_t ws_size,
                              hipStream_t stream) {
  const float* x    = (const float*)d_in[0];
  const float* w1   = (const float*)d_in[1];
  const float* w2   = (const float*)d_in[2];
  const float* dk   = (const float*)d_in[3];
  const float* bias = (const float*)d_in[4];
  float* out = (float*)d_out;

  const size_t R = 2048;
  const size_t L1 = 4099, L2 = 2053, L3 = 1030, L4 = 518;

  // fp32 region first (levels 3-4 + mixed), then bf16 region (levels 1-2).
  float* wf = (float*)d_ws;
  float* a3f = wf; wf += R * L3;
  float* d3f = wf; wf += R * L3;
  float* a4f = wf; wf += R * L4;
  float* d4f = wf; wf += R * L4;
  float* a4m = wf; wf += R * L4;
  float* d4m = wf; wf += R * L4;
  __hip_bfloat16* wb = (__hip_bfloat16*)wf;
  __hip_bfloat16* a1b = wb; wb += R * L1;  // later reused for recon1
  __hip_bfloat16* d1b = wb; wb += R * L1;
  __hip_bfloat16* a2b = wb; wb += R * L2;  // later reused for recon2
  __hip_bfloat16* d2b = wb; wb += R * L2;
  // total: 33.85 MB fp32 + 50.4 MB bf16 = 84.2 MB

  // Analysis
  k_dwt_first<<<dim3(65, 32), 256, 0, stream>>>(x, a1b, d1b);
  k_dwt<__hip_bfloat16, __hip_bfloat16>
      <<<dim3((2053 + 255) / 256, 2048), 256, 0, stream>>>(a1b, a2b, d2b, 4099, 2053);
  k_dwt<__hip_bfloat16, float>
      <<<dim3((1030 + 255) / 256, 2048), 256, 0, stream>>>(a2b, a3f, d3f, 2053, 1030);
  k_dwt<float, float>
      <<<dim3((518 + 255) / 256, 2048), 256, 0, stream>>>(a3f, a4f, d4f, 1030, 518);
  // Channel mixing
  k_mix<<<dim3((64 * 518 + 255) / 256, 32), 256, 0, stream>>>(a4f, d4f, w1, w2, a4m, d4m);
  // Synthesis (levels 3,2,1), reusing analysis buffers for recon
  k_idwt<float, float, float>
      <<<dim3((1030 + 255) / 256, 2048), 256, 0, stream>>>(a4m, d4m, a3f, 518, 1030);
  k_idwt<float, float, __hip_bfloat16>
      <<<dim3((2053 + 255) / 256, 2048), 256, 0, stream>>>(a3f, d3f, a2b, 1030, 2053);
  k_idwt<__hip_bfloat16, __hip_bfloat16, __hip_bfloat16>
      <<<dim3((4099 + 255) / 256, 2048), 256, 0, stream>>>(a2b, d2b, a1b, 2053, 4099);
  // Final level fused with dense shortcut + mish
  k_epilogue<<<dim3(128, 32), 256, 0, stream>>>(a1b, d1b, x, dk, bias, out);
}

// Round 4
// 323.246 us; speedup vs baseline: 1.1895x; 1.1895x over previous
//
#include <hip/hip_runtime.h>
#include <hip/hip_bf16.h>
#include <stdint.h>

typedef __attribute__((ext_vector_type(8))) short short8;
typedef __attribute__((ext_vector_type(4))) float floatx4;

// ---------------- db4 filter constants ----------------
__device__ __constant__ float c_DL[8] = {
    -0.010597401784997278f, 0.032883011666982945f, 0.030841381835986965f,
    -0.18703481171888114f, -0.02798376941698385f, 0.6308807679295904f,
    0.7148465705525415f, 0.23037781330885523f};
__device__ __constant__ float c_DH[8] = {
    -0.23037781330885523f, 0.7148465705525415f, -0.6308807679295904f,
    -0.02798376941698385f, 0.18703481171888114f, 0.030841381835986965f,
    -0.032883011666982945f, -0.010597401784997278f};
// REC_LO = reverse(DEC_LO) (also used as reversed-order analysis lowpass)
__device__ __constant__ float c_RL[8] = {
    0.23037781330885523f, 0.7148465705525415f, 0.6308807679295904f,
    -0.02798376941698385f, -0.18703481171888114f, 0.030841381835986965f,
    0.032883011666982945f, -0.010597401784997278f};
__device__ __constant__ float c_RH[8] = {
    -0.010597401784997278f, -0.032883011666982945f, 0.030841381835986965f,
    0.18703481171888114f, -0.02798376941698385f, -0.6308807679295904f,
    0.7148465705525415f, -0.23037781330885523f};

__device__ __forceinline__ float bflo(uint32_t u) { return __uint_as_float(u << 16); }
__device__ __forceinline__ float bfhi(uint32_t u) { return __uint_as_float(u & 0xffff0000u); }
__device__ __forceinline__ float ldf(const float* p, size_t i) { return p[i]; }
__device__ __forceinline__ float ldf(const __hip_bfloat16* p, size_t i) { return __bfloat162float(p[i]); }
__device__ __forceinline__ void stf(float* p, size_t i, float v) { p[i] = v; }
__device__ __forceinline__ void stf(__hip_bfloat16* p, size_t i, float v) { p[i] = __float2bfloat16(v); }
__device__ __forceinline__ short f2bs(float f) {
  __hip_bfloat16 h = __float2bfloat16(f);
  return *reinterpret_cast<short*>(&h);
}

__device__ __forceinline__ int reflect_idx(int t, int n) {
  if (t < 0) t = -1 - t;
  if (t >= n) t = 2 * n - 1 - t;
  return t;
}

// Row strides (padded for aligned vector access)
#define S1R 4100
#define S2R 2056

// ---------------- Level-1 DWT: x (B,N,C) fp32, transposed read -> a1,d1 (B*C, stride 4100) bf16
#define NT1 134
__global__ __launch_bounds__(256) void k_dwt_first(const float* __restrict__ x,
                                                   __hip_bfloat16* __restrict__ outa,
                                                   __hip_bfloat16* __restrict__ outd) {
  const int b = blockIdx.y;
  const int k0 = blockIdx.x * 64;
  const int tid = threadIdx.x;
  __shared__ float xs[NT1 * 65];

  const float4* x4 = (const float4*)x;
  for (int idx = tid; idx < NT1 * 16; idx += 256) {
    int nl = idx >> 4, cq = idx & 15;
    int t = 2 * k0 - 6 + nl;
    int n = reflect_idx(t, 8192);
    float4 v = x4[((size_t)b * 8192 + n) * 16 + cq];
    float* d = &xs[nl * 65 + 4 * cq];
    d[0] = v.x; d[1] = v.y; d[2] = v.z; d[3] = v.w;
  }
  __syncthreads();

  const int kk = tid & 63;
  const int k = k0 + kk;
  if (k >= 4099) return;
  for (int c = (tid >> 6); c < 64; c += 4) {
    float lo = 0.f, hi = 0.f;
#pragma unroll
    for (int j = 0; j < 8; ++j) {
      float v = xs[(2 * kk + 7 - j) * 65 + c];
      lo += c_DL[j] * v;
      hi += c_DH[j] * v;
    }
    size_t s = (size_t)b * 64 + c;
    outa[s * S1R + k] = __float2bfloat16(lo);
    outd[s * S1R + k] = __float2bfloat16(hi);
  }
}

// ---------------- Fused analysis levels 2..4, one row per block
__global__ __launch_bounds__(256) void k_ana234(const __hip_bfloat16* __restrict__ a1,
                                                __hip_bfloat16* __restrict__ d2o,
                                                float* __restrict__ d3o,
                                                float* __restrict__ a4o,
                                                float* __restrict__ d4o) {
  const int r = blockIdx.x;
  const int tid = threadIdx.x;
  __shared__ float s1[4100];
  __shared__ float s2[2054];
  __shared__ float s3[1032];

  const uint2* row2 = (const uint2*)(a1 + (size_t)r * S1R);
  for (int i = tid; i < 1025; i += 256) {
    uint2 u = row2[i];
    int e = 4 * i;
    s1[e] = bflo(u.x); s1[e + 1] = bfhi(u.x);
    s1[e + 2] = bflo(u.y); s1[e + 3] = bfhi(u.y);
  }
  __syncthreads();

  // level 2: n=4099 -> m=2053
  for (int k = tid; k < 2053; k += 256) {
    float lo = 0.f, hi = 0.f;
    if (k >= 3 && k <= 2048) {
      const float2* p = (const float2*)&s1[2 * k - 6];
      float2 v0 = p[0], v1 = p[1], v2 = p[2], v3 = p[3];
      lo = c_RL[0]*v0.x + c_RL[1]*v0.y + c_RL[2]*v1.x + c_RL[3]*v1.y +
           c_RL[4]*v2.x + c_RL[5]*v2.y + c_RL[6]*v3.x + c_RL[7]*v3.y;
      hi = c_RH[0]*v0.x + c_RH[1]*v0.y + c_RH[2]*v1.x + c_RH[3]*v1.y +
           c_RH[4]*v2.x + c_RH[5]*v2.y + c_RH[6]*v3.x + c_RH[7]*v3.y;
    } else {
#pragma unroll
      for (int j = 0; j < 8; ++j) {
        float v = s1[reflect_idx(2 * k + 1 - j, 4099)];
        lo += c_DL[j] * v; hi += c_DH[j] * v;
      }
    }
    d2o[(size_t)r * S2R + k] = __float2bfloat16(hi);
    s2[k] = lo;
  }
  __syncthreads();

  // level 3: n=2053 -> m=1030
  for (int k = tid; k < 1030; k += 256) {
    float lo = 0.f, hi = 0.f;
    if (k >= 3 && k <= 1025) {
      const float2* p = (const float2*)&s2[2 * k - 6];
      float2 v0 = p[0], v1 = p[1], v2 = p[2], v3 = p[3];
      lo = c_RL[0]*v0.x + c_RL[1]*v0.y + c_RL[2]*v1.x + c_RL[3]*v1.y +
           c_RL[4]*v2.x + c_RL[5]*v2.y + c_RL[6]*v3.x + c_RL[7]*v3.y;
      hi = c_RH[0]*v0.x + c_RH[1]*v0.y + c_RH[2]*v1.x + c_RH[3]*v1.y +
           c_RH[4]*v2.x + c_RH[5]*v2.y + c_RH[6]*v3.x + c_RH[7]*v3.y;
    } else {
#pragma unroll
      for (int j = 0; j < 8; ++j) {
        float v = s2[reflect_idx(2 * k + 1 - j, 2053)];
        lo += c_DL[j] * v; hi += c_DH[j] * v;
      }
    }
    d3o[(size_t)r * 1030 + k] = hi;
    s3[k] = lo;
  }
  __syncthreads();

  // level 4: n=1030 -> m=518
  for (int k = tid; k < 518; k += 256) {
    float lo = 0.f, hi = 0.f;
    if (k >= 3 && k <= 514) {
      const float2* p = (const float2*)&s3[2 * k - 6];
      float2 v0 = p[0], v1 = p[1], v2 = p[2], v3 = p[3];
      lo = c_RL[0]*v0.x + c_RL[1]*v0.y + c_RL[2]*v1.x + c_RL[3]*v1.y +
           c_RL[4]*v2.x + c_RL[5]*v2.y + c_RL[6]*v3.x + c_RL[7]*v3.y;
      hi = c_RH[0]*v0.x + c_RH[1]*v0.y + c_RH[2]*v1.x + c_RH[3]*v1.y +
           c_RH[4]*v2.x + c_RH[5]*v2.y + c_RH[6]*v3.x + c_RH[7]*v3.y;
    } else {
#pragma unroll
      for (int j = 0; j < 8; ++j) {
        float v = s3[reflect_idx(2 * k + 1 - j, 1030)];
        lo += c_DL[j] * v; hi += c_DH[j] * v;
      }
    }
    a4o[(size_t)r * 518 + k] = lo;
    d4o[(size_t)r * 518 + k] = hi;
  }
}

// ---------------- Channel mixing on coarsest coeffs (fp32)
__global__ void k_mix(const float* __restrict__ a4, const float* __restrict__ d4,
                      const float* __restrict__ w1, const float* __restrict__ w2,
                      float* __restrict__ am, float* __restrict__ dm) {
  int idx = blockIdx.x * blockDim.x + threadIdx.x;
  if (idx >= 64 * 518) return;
  int b = blockIdx.y;
  int o = idx / 518;
  int p = idx - o * 518;
  float sa = 0.f, sd = 0.f;
  for (int i = 0; i < 64; ++i) {
    float av = a4[(size_t)(b * 64 + i) * 518 + p];
    float dv = d4[(size_t)(b * 64 + i) * 518 + p];
    sa += av * w1[(size_t)(i * 64 + o) * 518 + p];
    sd += dv * w2[(size_t)(i * 64 + o) * 518 + p];
  }
  am[(size_t)(b * 64 + o) * 518 + p] = sa;
  dm[(size_t)(b * 64 + o) * 518 + p] = sd;
}

// ---------------- Fused synthesis: idwt level4->r3, then level3 -> recon2 (bf16)
__global__ __launch_bounds__(256) void k_syn32(const float* __restrict__ a4m,
                                               const float* __restrict__ d4m,
                                               const float* __restrict__ d3,
                                               __hip_bfloat16* __restrict__ r2out) {
  const int r = blockIdx.x;
  const int tid = threadIdx.x;
  __shared__ float sa[518], sd[518], s3d[1030], r3[1030];
  for (int i = tid; i < 518; i += 256) {
    sa[i] = a4m[(size_t)r * 518 + i];
    sd[i] = d4m[(size_t)r * 518 + i];
  }
  for (int i = tid; i < 1030; i += 256) s3d[i] = d3[(size_t)r * 1030 + i];
  __syncthreads();
  for (int s = tid; s < 1030; s += 256) {
    int u = s >> 1, par = s & 1;
    float acc = 0.f;
#pragma unroll
    for (int t = 0; t < 4; ++t) {
      int i = u + 3 - t;
      float fl = par ? c_RL[2 * t + 1] : c_RL[2 * t];
      float fh = par ? c_RH[2 * t + 1] : c_RH[2 * t];
      acc += fl * sa[i] + fh * sd[i];
    }
    r3[s] = acc;
  }
  __syncthreads();
  for (int s = tid; s < 2053; s += 256) {
    int u = s >> 1, par = s & 1;
    float acc = 0.f;
#pragma unroll
    for (int t = 0; t < 4; ++t) {
      int i = u + 3 - t;
      float fl = par ? c_RL[2 * t + 1] : c_RL[2 * t];
      float fh = par ? c_RH[2 * t + 1] : c_RH[2 * t];
      acc += fl * r3[i] + fh * s3d[i];
    }
    r2out[(size_t)r * S2R + s] = __float2bfloat16(acc);
  }
}

// ---------------- Generic IDWT level with strides (used for level 2 -> recon1)
template <typename TCa, typename TCd, typename TOut>
__global__ void k_idwt(const TCa* __restrict__ ca, const TCd* __restrict__ cd,
                       TOut* __restrict__ out, int m, int out_len, int sin, int sout) {
  int s = blockIdx.x * blockDim.x + threadIdx.x;
  if (s >= out_len) return;
  const TCa* pa = ca + (size_t)blockIdx.y * sin;
  const TCd* pd = cd + (size_t)blockIdx.y * sin;
  int u = s >> 1, par = s & 1;
  float acc = 0.f;
#pragma unroll
  for (int t = 0; t < 4; ++t) {
    int i = u + 3 - t;
    float fl = par ? c_RL[2 * t + 1] : c_RL[2 * t];
    float fh = par ? c_RH[2 * t + 1] : c_RH[2 * t];
    acc += fl * ldf(pa, i) + fh * ldf(pd, i);
  }
  stf(out, (size_t)blockIdx.y * sout + s, acc);
}

// ---------------- Epilogue: MFMA dense shortcut + final IDWT + bias + mish -> fp32
// block 256 (4 waves), tile 64n x 64o, grid (128, 32)
__global__ __launch_bounds__(256) void k_epilogue(const __hip_bfloat16* __restrict__ r1,
                                                  const __hip_bfloat16* __restrict__ dd1,
                                                  const float* __restrict__ x,
                                                  const float* __restrict__ dk,
                                                  const float* __restrict__ bias,
                                                  float* __restrict__ out) {
  const int b = blockIdx.y;
  const int n0 = blockIdx.x * 64;
  const int u0 = n0 >> 1;
  const int tid = threadIdx.x;
  const int lane = tid & 63;
  const int w = tid >> 6;

  __shared__ __hip_bfloat16 Kt[64 * 72];  // Kt[o][c], row pad to 72 (144B, 16B-aligned rows)
  __shared__ float ra[35 * 65];
  __shared__ float rd[35 * 65];

  // stage Kt = K^T (bf16)
  {
    const float4* dk4 = (const float4*)dk;
    for (int idx = tid; idx < 1024; idx += 256) {
      int c = idx >> 4, o0 = (idx & 15) * 4;
      float4 v = dk4[idx];  // dk[c][o0..o0+3]
      Kt[(o0 + 0) * 72 + c] = __float2bfloat16(v.x);
      Kt[(o0 + 1) * 72 + c] = __float2bfloat16(v.y);
      Kt[(o0 + 2) * 72 + c] = __float2bfloat16(v.z);
      Kt[(o0 + 3) * 72 + c] = __float2bfloat16(v.w);
    }
  }
  // stage ra/rd (35 coeffs x 64 channels)
  {
    int o2 = tid >> 2;
    const __hip_bfloat16* pr = r1 + (size_t)(b * 64 + o2) * S1R + u0;
    const __hip_bfloat16* pd = dd1 + (size_t)(b * 64 + o2) * S1R + u0;
    for (int il = (tid & 3); il < 35; il += 4) {
      ra[il * 65 + o2] = __bfloat162float(pr[il]);
      rd[il * 65 + o2] = __bfloat162float(pd[il]);
    }
  }
  __syncthreads();

  const int m16 = lane & 15;        // A-row within 16-tile / B-col within o-tile
  const int kq = (lane >> 4) * 8;   // k sub-offset
  const int nrow = w * 16 + m16;    // this lane's A row (n_loc) for loading
  const float* xrow = x + ((size_t)b * 8192 + n0 + nrow) * 64;

  floatx4 acc[4];
#pragma unroll
  for (int ot = 0; ot < 4; ++ot) acc[ot] = (floatx4){0.f, 0.f, 0.f, 0.f};

#pragma unroll
  for (int ks = 0; ks < 2; ++ks) {
    float4 xa = *(const float4*)(xrow + ks * 32 + kq);
    float4 xb = *(const float4*)(xrow + ks * 32 + kq + 4);
    short8 af;
    af[0] = f2bs(xa.x); af[1] = f2bs(xa.y); af[2] = f2bs(xa.z); af[3] = f2bs(xa.w);
    af[4] = f2bs(xb.x); af[5] = f2bs(xb.y); af[6] = f2bs(xb.z); af[7] = f2bs(xb.w);
#pragma unroll
    for (int ot = 0; ot < 4; ++ot) {
      short8 bf = *(const short8*)&Kt[(ot * 16 + m16) * 72 + ks * 32 + kq];
      acc[ot] = __builtin_amdgcn_mfma_f32_16x16x32_bf16(af, bf, acc[ot], 0, 0, 0);
    }
  }

  // epilogue: C/D layout col=lane&15 (o), row=(lane>>4)*4+reg (n)
  const int rbase = (lane >> 4) * 4;
#pragma unroll
  for (int ot = 0; ot < 4; ++ot) {
    int o_loc = ot * 16 + m16;
    float bo = bias[o_loc];
#pragma unroll
    for (int rg = 0; rg < 4; ++rg) {
      int n_loc = w * 16 + rbase + rg;
      int ul = n_loc >> 1, par = n_loc & 1;
      float wv = 0.f;
#pragma unroll
      for (int t = 0; t < 4; ++t) {
        int i = ul + 3 - t;
        float fl = par ? c_RL[2 * t + 1] : c_RL[2 * t];
        float fh = par ? c_RH[2 * t + 1] : c_RH[2 * t];
        wv += fl * ra[i * 65 + o_loc] + fh * rd[i * 65 + o_loc];
      }
      float v = acc[ot][rg] + wv + bo;
      float e = __expf(fminf(v, 15.f));
      float num = e * (e + 2.f);
      float mm = (v > 15.f) ? v : v * (num / (num + 2.f));
      out[((size_t)b * 8192 + n0 + n_loc) * 64 + o_loc] = mm;
    }
  }
}

// ---------------- host ----------------
extern "C" void kernel_launch(void* const* d_in, const int* in_sizes, int n_in,
                              void* d_out, int out_size, void* d_ws, size_t ws_size,
                              hipStream_t stream) {
  const float* x    = (const float*)d_in[0];
  const float* w1   = (const float*)d_in[1];
  const float* w2   = (const float*)d_in[2];
  const float* dk   = (const float*)d_in[3];
  const float* bias = (const float*)d_in[4];
  float* out = (float*)d_out;

  const size_t R = 2048;

  float* wf = (float*)d_ws;
  float* d3f = wf; wf += R * 1030;
  float* a4f = wf; wf += R * 518;
  float* d4f = wf; wf += R * 518;
  float* a4m = wf; wf += R * 518;
  float* d4m = wf; wf += R * 518;
  __hip_bfloat16* wb = (__hip_bfloat16*)wf;
  __hip_bfloat16* a1b = wb; wb += R * S1R;  // analysis a1, later recon1
  __hip_bfloat16* d1b = wb; wb += R * S1R;
  __hip_bfloat16* a2b = wb; wb += R * S2R;  // analysis a2 unused; holds recon2
  __hip_bfloat16* d2b = wb; wb += R * S2R;
  // total ~75.8 MB

  k_dwt_first<<<dim3(65, 32), 256, 0, stream>>>(x, a1b, d1b);
  k_ana234<<<dim3(2048), 256, 0, stream>>>(a1b, d2b, d3f, a4f, d4f);
  k_mix<<<dim3((64 * 518 + 255) / 256, 32), 256, 0, stream>>>(a4f, d4f, w1, w2, a4m, d4m);
  k_syn32<<<dim3(2048), 256, 0, stream>>>(a4m, d4m, d3f, a2b);
  k_idwt<__hip_bfloat16, __hip_bfloat16, __hip_bfloat16>
      <<<dim3((4099 + 255) / 256, 2048), 256, 0, stream>>>(a2b, d2b, a1b, 2053, 4099, S2R, S1R);
  k_epilogue<<<dim3(128, 32), 256, 0, stream>>>(a1b, d1b, x, dk, bias, out);
}